// Round 1
// baseline (1280.982 us; speedup 1.0000x reference)
//
#include <hip/hip_runtime.h>
#include <math.h>

#define HIDDEN 128

// Kernel 1: compute segment start offsets from the sorted segment_ids array.
// offs[g] = first node index i with seg[i] >= g;  offs[num_seg] = n.
// Handles empty segments (a boundary thread fills the whole skipped range).
__global__ void seg_bounds_kernel(const int* __restrict__ seg,
                                  int* __restrict__ offs,
                                  int n, int num_seg) {
    int i = blockIdx.x * blockDim.x + threadIdx.x;
    if (i > n) return;
    int cur  = (i < n) ? seg[i]     : num_seg;
    int prev = (i > 0) ? seg[i - 1] : -1;
    for (int g = prev + 1; g <= cur; ++g) offs[g] = i;
}

// Kernel 2: one 64-lane wave per segment. The wave is split into two 32-lane
// halves; each half owns one row per loop iteration (rows r=start+half, step 2).
// Per row: float4 load (64 lanes x 16B = 1KB per wave instr = 2 rows),
// 5-step shfl_xor dot-product reduction, then an online-softmax (running
// max m, denom d, weighted accumulator acc) update entirely in registers --
// so x is read from HBM exactly ONCE.
__global__ __launch_bounds__(256, 8)
void attn_pool_kernel(const float* __restrict__ x,
                      const float* __restrict__ w,
                      const int* __restrict__ offs,
                      float* __restrict__ out,
                      int num_seg) {
    const int g = blockIdx.x * 4 + (threadIdx.x >> 6);
    if (g >= num_seg) return;
    const int lane = threadIdx.x & 63;
    const int half = lane >> 5;   // which row of the current pair
    const int sub  = lane & 31;   // column group: 4 consecutive floats per lane

    const float4 wv = *reinterpret_cast<const float4*>(w + (sub << 2));

    const int start = offs[g];
    const int end   = offs[g + 1];

    if (end <= start) {           // empty segment -> zeros (matches reference)
        if (half == 0) {
            *reinterpret_cast<float4*>(out + (size_t)g * HIDDEN + (sub << 2)) =
                make_float4(0.f, 0.f, 0.f, 0.f);
        }
        return;
    }

    float  m    = -INFINITY;
    float  dsum = 0.f;
    float4 acc  = make_float4(0.f, 0.f, 0.f, 0.f);

    for (int r = start + half; r < end; r += 2) {
        const float4 v = *reinterpret_cast<const float4*>(
            x + (size_t)r * HIDDEN + (sub << 2));
        float p = v.x * wv.x + v.y * wv.y + v.z * wv.z + v.w * wv.w;
        // reduce across the 32-lane half (xor masks 1..16 never cross bit 5)
        p += __shfl_xor(p, 1);
        p += __shfl_xor(p, 2);
        p += __shfl_xor(p, 4);
        p += __shfl_xor(p, 8);
        p += __shfl_xor(p, 16);
        // online softmax update
        const float mn = fmaxf(m, p);
        const float sc = __expf(m - mn);   // == 0 on first iteration (m=-inf)
        const float e  = __expf(p - mn);
        dsum  = dsum  * sc + e;
        acc.x = acc.x * sc + v.x * e;
        acc.y = acc.y * sc + v.y * e;
        acc.z = acc.z * sc + v.z * e;
        acc.w = acc.w * sc + v.w * e;
        m = mn;
    }

    // merge the two half-wave online-softmax states (symmetric: both halves
    // compute identical merged values; -inf half (odd count / 1-row segment)
    // contributes exp(-inf)=0 safely since the other m is finite).
    const float m1 = __shfl_xor(m, 32);
    const float d1 = __shfl_xor(dsum, 32);
    float4 a1;
    a1.x = __shfl_xor(acc.x, 32);
    a1.y = __shfl_xor(acc.y, 32);
    a1.z = __shfl_xor(acc.z, 32);
    a1.w = __shfl_xor(acc.w, 32);

    const float mf = fmaxf(m, m1);
    const float s0 = __expf(m - mf);
    const float s1 = __expf(m1 - mf);
    const float df = dsum * s0 + d1 * s1;   // > 0 for non-empty segments
    const float inv = 1.0f / df;

    if (half == 0) {
        float4 o;
        o.x = (acc.x * s0 + a1.x * s1) * inv;
        o.y = (acc.y * s0 + a1.y * s1) * inv;
        o.z = (acc.z * s0 + a1.z * s1) * inv;
        o.w = (acc.w * s0 + a1.w * s1) * inv;
        *reinterpret_cast<float4*>(out + (size_t)g * HIDDEN + (sub << 2)) = o;
    }
}

extern "C" void kernel_launch(void* const* d_in, const int* in_sizes, int n_in,
                              void* d_out, int out_size, void* d_ws, size_t ws_size,
                              hipStream_t stream) {
    const float* x   = (const float*)d_in[0];
    const float* w   = (const float*)d_in[1];
    const int*   seg = (const int*)d_in[2];
    float*       out = (float*)d_out;

    const int n       = in_sizes[2];          // number of nodes
    const int num_seg = out_size / HIDDEN;    // 8192
    int* offs = (int*)d_ws;                   // num_seg+1 ints of scratch

    {
        const int threads = 256;
        const int blocks  = (n + 1 + threads - 1) / threads;
        seg_bounds_kernel<<<blocks, threads, 0, stream>>>(seg, offs, n, num_seg);
    }
    {
        const int blocks = (num_seg + 3) / 4;  // one wave (of 4 per block) per segment
        attn_pool_kernel<<<blocks, 256, 0, stream>>>(x, w, offs, out, num_seg);
    }
}

// Round 6
// 1277.460 us; speedup vs baseline: 1.0028x; 1.0028x over previous
//
#include <hip/hip_runtime.h>
#include <math.h>

#define HIDDEN 128
#define NEG_BIG (-3.0e38f)

// Kernel 1: segment start offsets from sorted ids.
// offs[g] = first i with seg[i] >= g; offs[num_seg] = n. Empty segs handled.
__global__ void seg_bounds_kernel(const int* __restrict__ seg,
                                  int* __restrict__ offs,
                                  int n, int num_seg) {
    int i = blockIdx.x * blockDim.x + threadIdx.x;
    if (i > n) return;
    int cur  = (i < n) ? seg[i]     : num_seg;
    int prev = (i > 0) ? seg[i - 1] : -1;
    for (int g = prev + 1; g <= cur; ++g) offs[g] = i;
}

// Kernel 2: one wave per segment, single pass over x (read exactly once).
// Wave = 4 row-groups of 16 lanes. Each group owns one row per iteration
// (rows row..row+3 -> 2KB contiguous per wave-iteration). Each lane holds
// 8 floats (2 float4) of its row. Row dot-product reduced in 4 shfl_xor
// steps (within 16 lanes, all 4 rows reduced by the same 4 wave instrs).
// Online softmax state (m, dsum, 8-float acc slice) kept per lane; the 4
// group states are merged at the end with 2 shuffle-rescale steps.
__global__ __launch_bounds__(256, 4)
void attn_pool_kernel(const float* __restrict__ x,
                      const float* __restrict__ w,
                      const int* __restrict__ offs,
                      float* __restrict__ out,
                      int num_seg) {
    const int g = blockIdx.x * 4 + (threadIdx.x >> 6);
    if (g >= num_seg) return;
    const int lane = threadIdx.x & 63;
    const int grp  = lane >> 4;   // row-group 0..3
    const int sub  = lane & 15;   // column slice: floats [sub*8, sub*8+8)

    const float4 wa = *reinterpret_cast<const float4*>(w + sub * 8);
    const float4 wb = *reinterpret_cast<const float4*>(w + sub * 8 + 4);

    const int start = offs[g];
    const int end   = offs[g + 1];

    if (end <= start) {          // empty segment -> zeros (matches reference)
        if (lane < 16) {
            const float4 z = make_float4(0.f, 0.f, 0.f, 0.f);
            float* o = out + (size_t)g * HIDDEN + sub * 8;
            *reinterpret_cast<float4*>(o)     = z;
            *reinterpret_cast<float4*>(o + 4) = z;
        }
        return;
    }

    float  m = NEG_BIG, dsum = 0.f;
    float4 acca = make_float4(0.f, 0.f, 0.f, 0.f);
    float4 accb = make_float4(0.f, 0.f, 0.f, 0.f);

    const int cnt = end - start;
    const int L   = (cnt + 3) >> 2;     // iterations (4 rows each)

    int row  = start + grp;
    {
        // prefetch first row for this group (clamped; inactive contributes 0)
        int rowc = min(row, end - 1);
        const float* p0 = x + (size_t)rowc * HIDDEN + sub * 8;
        float4 a = reinterpret_cast<const float4*>(p0)[0];
        float4 b = reinterpret_cast<const float4*>(p0)[1];

        for (int i = 0; i < L; ++i) {
            const int rown = row + 4;
            float4 an = make_float4(0.f, 0.f, 0.f, 0.f);
            float4 bn = make_float4(0.f, 0.f, 0.f, 0.f);
            if (i + 1 < L) {
                const int rowcn = min(rown, end - 1);
                const float* pn = x + (size_t)rowcn * HIDDEN + sub * 8;
                an = reinterpret_cast<const float4*>(pn)[0];
                bn = reinterpret_cast<const float4*>(pn)[1];
            }

            // row score: per-lane partial dot, then 4-step reduce over 16 lanes
            float p = a.x * wa.x + a.y * wa.y + a.z * wa.z + a.w * wa.w
                    + b.x * wb.x + b.y * wb.y + b.z * wb.z + b.w * wb.w;
            p += __shfl_xor(p, 1);
            p += __shfl_xor(p, 2);
            p += __shfl_xor(p, 4);
            p += __shfl_xor(p, 8);

            const bool act = (row < end);          // uniform within the group
            p = act ? p : NEG_BIG;

            const float mn = fmaxf(m, p);
            const float sc = __expf(m - mn);       // finite operands, no NaN
            const float e  = act ? __expf(p - mn) : 0.f;

            dsum   = dsum   * sc + e;
            acca.x = acca.x * sc + a.x * e;
            acca.y = acca.y * sc + a.y * e;
            acca.z = acca.z * sc + a.z * e;
            acca.w = acca.w * sc + a.w * e;
            accb.x = accb.x * sc + b.x * e;
            accb.y = accb.y * sc + b.y * e;
            accb.z = accb.z * sc + b.z * e;
            accb.w = accb.w * sc + b.w * e;
            m = mn;

            a = an; b = bn; row = rown;
        }
    }

    // merge the 4 group states (xor 16, then 32); all finite, no NaN paths
    #pragma unroll
    for (int mask = 16; mask <= 32; mask <<= 1) {
        const float mo = __shfl_xor(m, mask);
        const float d1 = __shfl_xor(dsum, mask);
        float4 ao, bo;
        ao.x = __shfl_xor(acca.x, mask);
        ao.y = __shfl_xor(acca.y, mask);
        ao.z = __shfl_xor(acca.z, mask);
        ao.w = __shfl_xor(acca.w, mask);
        bo.x = __shfl_xor(accb.x, mask);
        bo.y = __shfl_xor(accb.y, mask);
        bo.z = __shfl_xor(accb.z, mask);
        bo.w = __shfl_xor(accb.w, mask);

        const float mf = fmaxf(m, mo);
        const float s0 = __expf(m  - mf);
        const float s1 = __expf(mo - mf);
        dsum   = dsum * s0 + d1 * s1;
        acca.x = acca.x * s0 + ao.x * s1;
        acca.y = acca.y * s0 + ao.y * s1;
        acca.z = acca.z * s0 + ao.z * s1;
        acca.w = acca.w * s0 + ao.w * s1;
        accb.x = accb.x * s0 + bo.x * s1;
        accb.y = accb.y * s0 + bo.y * s1;
        accb.z = accb.z * s0 + bo.z * s1;
        accb.w = accb.w * s0 + bo.w * s1;
        m = mf;
    }

    if (lane < 16) {
        const float inv = 1.0f / dsum;   // dsum > 0 for non-empty segments
        float4 oa, ob;
        oa.x = acca.x * inv; oa.y = acca.y * inv;
        oa.z = acca.z * inv; oa.w = acca.w * inv;
        ob.x = accb.x * inv; ob.y = accb.y * inv;
        ob.z = accb.z * inv; ob.w = accb.w * inv;
        float* o = out + (size_t)g * HIDDEN + sub * 8;
        *reinterpret_cast<float4*>(o)     = oa;
        *reinterpret_cast<float4*>(o + 4) = ob;
    }
}

extern "C" void kernel_launch(void* const* d_in, const int* in_sizes, int n_in,
                              void* d_out, int out_size, void* d_ws, size_t ws_size,
                              hipStream_t stream) {
    const float* x   = (const float*)d_in[0];
    const float* w   = (const float*)d_in[1];
    const int*   seg = (const int*)d_in[2];
    float*       out = (float*)d_out;

    const int n       = in_sizes[2];          // number of nodes
    const int num_seg = out_size / HIDDEN;    // 8192
    int* offs = (int*)d_ws;                   // num_seg+1 ints of scratch

    {
        const int threads = 256;
        const int blocks  = (n + 1 + threads - 1) / threads;
        seg_bounds_kernel<<<blocks, threads, 0, stream>>>(seg, offs, n, num_seg);
    }
    {
        const int blocks = (num_seg + 3) / 4;  // one wave per segment
        attn_pool_kernel<<<blocks, 256, 0, stream>>>(x, w, offs, out, num_seg);
    }
}